// Round 14
// baseline (320.446 us; speedup 1.0000x reference)
//
#include <hip/hip_runtime.h>
#include <hip/hip_bf16.h>

#define NN 20000
#define EE 320000
#define GG 256

__device__ __forceinline__ float lanebc(float v, int l){
  return __uint_as_float(__builtin_amdgcn_readlane(__float_as_uint(v), (unsigned)l));
}
__device__ __forceinline__ int lanebci(int v, int l){
  return __builtin_amdgcn_readlane(v, (unsigned)l);
}
__device__ __forceinline__ float wave_sum(float v){
  #pragma unroll
  for(int m=32;m>0;m>>=1) v += __shfl_xor(v, m, 64);
  return v;
}
__device__ __forceinline__ float elu(float o){
  return (o > 0.f) ? o : (__expf(o) - 1.f);
}
// softmax exp without max-pass: shift-invariant, clamp prevents overflow (scores are O(5))
__device__ __forceinline__ float pexp(float e){ return __expf(fminf(e, 60.f)); }
// bf16 pack/unpack
__device__ __forceinline__ float bf2f(ushort u){ return __uint_as_float((unsigned)u << 16); }
__device__ __forceinline__ ushort f2bf(float f){
  unsigned x = __float_as_uint(f);
  return (ushort)((x + 0x7FFFu + ((x >> 16) & 1u)) >> 16);
}
__device__ __forceinline__ float2 up2(unsigned w){
  return make_float2(__uint_as_float(w << 16), __uint_as_float(w & 0xFFFF0000u));
}

// ---------------- merged front: node-MLP+xlxr1 (blocks 0..2499), edge_acc (2500..22499),
// weights prep (22500..22549). All three are mutually independent. ----------------
__global__ __launch_bounds__(256) void k_front(
    const float* __restrict__ x, const float* __restrict__ Wcat,
    const float* __restrict__ bcat, const float* __restrict__ Wini,
    const float* __restrict__ bini, const float* __restrict__ Wl,
    const float* __restrict__ bl, const float* __restrict__ Wr,
    const float* __restrict__ br, ushort* __restrict__ h0b,
    ushort* __restrict__ xl, ushort* __restrict__ xr,
    const int* __restrict__ ei, const float* __restrict__ ea,
    float* __restrict__ loopA, int* __restrict__ cnt,
    const float* __restrict__ We9, const float* __restrict__ be,
    const float* __restrict__ We1, const float* __restrict__ We2,
    const float* __restrict__ Wl2, const float* __restrict__ Wr2,
    float* __restrict__ Wf1, float* __restrict__ bf1,
    float* __restrict__ Wf2, float* __restrict__ bf2,
    float4* __restrict__ Wl1p4, float4* __restrict__ Wl2p4,
    float4* __restrict__ Wr2p4)
{
  const int tid = threadIdx.x;
  __shared__ float xs[8][25];
  __shared__ float sv[8][33];
  __shared__ __align__(16) float hsT[64][8];

  if (blockIdx.x < 2500) {
    // ---- fused node-MLP + layer-1 transform (identical to k_xlxr1f) ----
    const int n0 = blockIdx.x*8;
    if (tid < 192){ int n=tid/24, j=tid%24; xs[n][j] = x[(size_t)(n0+n)*24 + j]; }
    __syncthreads();
    {
      const int n = tid>>5, cc = tid&31;
      float a = bcat[cc];
      #pragma unroll
      for (int k=0;k<16;k++) a += xs[n][k]*Wcat[k*32+cc];
      sv[n][cc] = fmaxf(a, 0.f);
    }
    __syncthreads();
    #pragma unroll
    for (int i=tid;i<512;i+=256){
      const int n = i>>6, c = i&63;
      float a = bini[c];
      #pragma unroll
      for (int k=0;k<8;k++)  a += xs[n][16+k]*Wini[k*64+c];
      #pragma unroll
      for (int k=0;k<32;k++) a += sv[n][k]*Wini[(8+k)*64+c];
      const float r = fmaxf(a, 0.f);
      hsT[c][n] = r;
      h0b[(size_t)(n0+n)*64 + c] = f2bf(r);
    }
    __syncthreads();
    const int c = tid;   // 256
    float accl[8], accr[8];
    const float blv = bl[c], brv = br[c];
    #pragma unroll
    for(int n=0;n<8;n++){ accl[n]=blv; accr[n]=brv; }
    for(int k=0;k<64;k++){
      const float wl = Wl[k*256 + c];
      const float wr = Wr[k*256 + c];
      const float4 ha = *(const float4*)&hsT[k][0];
      const float4 hb = *(const float4*)&hsT[k][4];
      accl[0]+=ha.x*wl; accr[0]+=ha.x*wr; accl[1]+=ha.y*wl; accr[1]+=ha.y*wr;
      accl[2]+=ha.z*wl; accr[2]+=ha.z*wr; accl[3]+=ha.w*wl; accr[3]+=ha.w*wr;
      accl[4]+=hb.x*wl; accr[4]+=hb.x*wr; accl[5]+=hb.y*wl; accr[5]+=hb.y*wr;
      accl[6]+=hb.z*wl; accr[6]+=hb.z*wr; accl[7]+=hb.w*wl; accr[7]+=hb.w*wr;
    }
    #pragma unroll
    for(int n=0;n<8;n++){
      xl[(size_t)(n0+n)*256 + c] = f2bf(accl[n]);
      xr[(size_t)(n0+n)*256 + c] = f2bf(accr[n]);
    }
  } else if (blockIdx.x < 22500) {
    // ---- per-target ea sums (self-loop mean) + in-degree (identical to k_edge_acc) ----
    const int g = (blockIdx.x-2500)*16 + (tid>>4);
    const int j = tid & 15;
    if (g >= EE) return;
    const int t = ei[EE + g];
    if (j < 9)       atomicAdd(&loopA[t*12 + j], ea[(size_t)g*9 + j]);
    else if (j == 9) atomicAdd(&cnt[t], 1);
  } else {
    // ---- weights prep (identical to k_weights) ----
    const int b = blockIdx.x - 22500;
    if (b < 48){
      const int idx = (b%16)*256 + tid;
      const int seg = b/16;
      if (seg == 0){
        const int k4 = idx>>8, c = idx&255;
        Wl1p4[idx] = make_float4(Wl[(4*k4+0)*256+c], Wl[(4*k4+1)*256+c],
                                 Wl[(4*k4+2)*256+c], Wl[(4*k4+3)*256+c]);
      } else if (seg == 1){
        const int k4 = idx>>6, cc = idx&63;
        Wl2p4[idx] = make_float4(Wl2[(4*k4+0)*64+cc], Wl2[(4*k4+1)*64+cc],
                                 Wl2[(4*k4+2)*64+cc], Wl2[(4*k4+3)*64+cc]);
      } else {
        const int k4 = idx>>6, cc = idx&63;
        Wr2p4[idx] = make_float4(Wr2[(4*k4+0)*64+cc], Wr2[(4*k4+1)*64+cc],
                                 Wr2[(4*k4+2)*64+cc], Wr2[(4*k4+3)*64+cc]);
      }
    } else if (b == 48){
      const int c = tid; // 256
      #pragma unroll
      for (int j=0;j<9;j++){
        float a = 0.f;
        #pragma unroll
        for (int k=0;k<32;k++) a += We9[j*32+k]*We1[k*256+c];
        Wf1[j*256+c] = a;
      }
      float bb = 0.f;
      #pragma unroll
      for (int k=0;k<32;k++) bb += be[k]*We1[k*256+c];
      bf1[c] = bb;
    } else {
      if (tid < 64){
        const int c = tid;
        #pragma unroll
        for (int j=0;j<9;j++){
          float a = 0.f;
          #pragma unroll
          for (int k=0;k<32;k++) a += We9[j*32+k]*We2[k*64+c];
          Wf2[j*64+c] = a;
        }
        float bb = 0.f;
        #pragma unroll
        for (int k=0;k<32;k++) bb += be[k]*We2[k*64+c];
        bf2[c] = bb;
      }
    }
  }
}

__global__ void k_alloc(const int* __restrict__ cnt, int* __restrict__ start, int* __restrict__ counter){
  int i = blockIdx.x*blockDim.x + threadIdx.x;
  if (i < NN) start[i] = atomicAdd(counter, cnt[i]);
}

__global__ void k_scatter(const int* __restrict__ ei, const int* __restrict__ start,
                          int* __restrict__ fill, int* __restrict__ csr,
                          int* __restrict__ srcp, int* __restrict__ tgtp){
  int e = blockIdx.x*blockDim.x + threadIdx.x;
  if (e >= EE) return;
  int t = ei[EE + e];
  int p = start[t] + atomicAdd(&fill[t], 1);
  csr[p] = e;
  srcp[p] = ei[e];
  tgtp[p] = t;
}

// ---------------- edge-parallel GATv2 scores (K=9 folded, bf16 gathers) ----------------
// esc layout: [head][EE], stores RAW scores. EXACT round-10 codegen — epilogue is
// codegen-fragile: any change (store layout, transcendental in store path) triples VGPR.
template<int F>
__global__ __launch_bounds__(256) void k_score(const float* __restrict__ ea, const int* __restrict__ csr,
                        const int* __restrict__ srcp, const int* __restrict__ tgtp,
                        const ushort* __restrict__ xl, const ushort* __restrict__ xr,
                        const float* __restrict__ Wf, const float* __restrict__ bf,
                        const float* __restrict__ att, float* __restrict__ esc)
{
  constexpr int HP  = (F == 256) ? 2 : 1;
  constexpr int CPL = (F == 256) ? 8 : 4;
  const int tid  = threadIdx.x;
  const int lane = tid & 63;
  const int w    = tid >> 6;
  const int p0   = blockIdx.x * 64;

  __shared__ float ea_sT[9][64];
  __shared__ float Wf_s[9*F];
  __shared__ float bf_s[F];
  __shared__ int csr_s[64], src_s[64], tgt_s[64];

  if (tid < 64) { csr_s[tid] = csr[p0+tid]; src_s[tid] = srcp[p0+tid]; tgt_s[tid] = tgtp[p0+tid]; }
  __syncthreads();
  for (int i = tid; i < 576; i += 256){ int j = i>>6, ed = i&63; ea_sT[j][ed] = ea[(size_t)csr_s[ed]*9 + j]; }
  for (int i = tid; i < (9*F)/4; i += 256) ((float4*)Wf_s)[i] = ((const float4*)Wf)[i];
  if (tid < F) bf_s[tid] = bf[tid];
  __syncthreads();

  const int g = lane >> 4, t = lane & 15;
  const int eb = w*16 + g*4;

  #pragma unroll
  for (int hp = 0; hp < HP; ++hp) {
    const int c = hp*(F/HP) + t*CPL;
    float bfv[CPL];
    *(float4*)&bfv[0] = *(const float4*)&bf_s[c];
    if (CPL==8) *(float4*)&bfv[4] = *(const float4*)&bf_s[c+4];
    float acc[4][CPL];
    #pragma unroll
    for (int j=0;j<4;j++)
      #pragma unroll
      for(int q=0;q<CPL;q++) acc[j][q]=bfv[q];
    #pragma unroll
    for (int k=0;k<9;k++){
      const float4 ev = *(const float4*)&ea_sT[k][eb];
      float wv[CPL];
      *(float4*)&wv[0] = *(const float4*)&Wf_s[k*F + c];
      if (CPL==8) *(float4*)&wv[4] = *(const float4*)&Wf_s[k*F + c + 4];
      #pragma unroll
      for (int q=0;q<CPL;q++){
        acc[0][q] += ev.x*wv[q]; acc[1][q] += ev.y*wv[q];
        acc[2][q] += ev.z*wv[q]; acc[3][q] += ev.w*wv[q];
      }
    }
    float attv[CPL];
    *(float4*)&attv[0] = *(const float4*)&att[c];
    if (CPL==8) *(float4*)&attv[4] = *(const float4*)&att[c+4];
    float partial[4];
    #pragma unroll
    for (int j=0;j<4;j++){
      const int s  = src_s[eb+j];
      const int tg = tgt_s[eb+j];
      float xlv[CPL], xrv[CPL];
      if (CPL==8){
        const uint4 a = *(const uint4*)&xl[(size_t)s*F + c];
        const uint4 b = *(const uint4*)&xr[(size_t)tg*F + c];
        float2 p;
        p=up2(a.x); xlv[0]=p.x; xlv[1]=p.y;  p=up2(a.y); xlv[2]=p.x; xlv[3]=p.y;
        p=up2(a.z); xlv[4]=p.x; xlv[5]=p.y;  p=up2(a.w); xlv[6]=p.x; xlv[7]=p.y;
        p=up2(b.x); xrv[0]=p.x; xrv[1]=p.y;  p=up2(b.y); xrv[2]=p.x; xrv[3]=p.y;
        p=up2(b.z); xrv[4]=p.x; xrv[5]=p.y;  p=up2(b.w); xrv[6]=p.x; xrv[7]=p.y;
      } else {
        const uint2 a = *(const uint2*)&xl[(size_t)s*F + c];
        const uint2 b = *(const uint2*)&xr[(size_t)tg*F + c];
        float2 p;
        p=up2(a.x); xlv[0]=p.x; xlv[1]=p.y;  p=up2(a.y); xlv[2]=p.x; xlv[3]=p.y;
        p=up2(b.x); xrv[0]=p.x; xrv[1]=p.y;  p=up2(b.y); xrv[2]=p.x; xrv[3]=p.y;
      }
      float sum = 0.f;
      #pragma unroll
      for (int q=0;q<CPL;q++){
        float m = acc[j][q] + xlv[q] + xrv[q];
        m = (m >= 0.f) ? m : 0.2f*m;
        sum += attv[q]*m;
      }
      partial[j] = sum;
    }
    #pragma unroll
    for (int j=0;j<4;j++){
      partial[j] += __shfl_xor(partial[j], 1, 64);
      partial[j] += __shfl_xor(partial[j], 2, 64);
      partial[j] += __shfl_xor(partial[j], 4, 64);
      if (F==64) partial[j] += __shfl_xor(partial[j], 8, 64);
    }
    if (F==256){
      if ((t & 7) == 0){
        const int h = hp*2 + (t>>3);
        #pragma unroll
        for (int j=0;j<4;j++) esc[(size_t)h*EE + p0 + eb + j] = partial[j];
      }
    } else {
      if (t == 0){
        #pragma unroll
        for (int j=0;j<4;j++) esc[p0 + eb + j] = partial[j];
      }
    }
  }
}

// ---------------- layer-1 softmax + h-space aggregate (no max pass): zb[N,4,64] bf16 ----------------
__global__ __launch_bounds__(256) void k_agg1(
    const float* __restrict__ loopA, const int* __restrict__ cnt,
    const int* __restrict__ start, const int* __restrict__ srcp,
    const ushort* __restrict__ h0b, const ushort* __restrict__ xl, const ushort* __restrict__ xr,
    const float* __restrict__ Wf, const float* __restrict__ bf,
    const float* __restrict__ att, const float* __restrict__ esc,
    ushort* __restrict__ zb)
{
  const int t = blockIdx.x*4 + (threadIdx.x>>6);
  const int c = threadIdx.x & 63;
  const int st = start[t], dg = cnt[t];

  float epb[4];
  if (dg > 0){
    const float invc = 1.f/(float)dg;
    float la[9];
    #pragma unroll
    for (int j=0;j<9;j++) la[j] = loopA[t*12+j]*invc;
    #pragma unroll
    for (int hd=0;hd<4;hd++){
      float ep = bf[hd*64+c];
      #pragma unroll
      for (int j=0;j<9;j++) ep += la[j]*Wf[j*256 + hd*64 + c];
      epb[hd] = ep;
    }
  } else {
    #pragma unroll
    for (int hd=0;hd<4;hd++) epb[hd]=0.f;
  }
  const float h0t = bf2f(h0b[(size_t)t*64 + c]);
  float preg[4], den[4], z[4];
  #pragma unroll
  for (int hd=0;hd<4;hd++){
    float m = bf2f(xl[(size_t)t*256 + hd*64 + c]) + bf2f(xr[(size_t)t*256 + hd*64 + c]) + epb[hd];
    m = (m>=0.f)? m : 0.2f*m;
    const float pS = pexp(wave_sum(att[hd*64+c]*m));
    den[hd] = pS;
    z[hd] = pS*h0t;
  }

  int sL = 0;
  #pragma unroll
  for (int hd=0;hd<4;hd++) preg[hd] = 0.f;
  if (c < dg){
    sL = srcp[st+c];
    #pragma unroll
    for (int hd=0;hd<4;hd++) preg[hd] = pexp(esc[(size_t)hd*EE + st + c]);
  }
  #pragma unroll
  for (int hd=0;hd<4;hd++) den[hd] += wave_sum(preg[hd]);

  const int d1 = min(dg,64);
  for (int i=0;i<d1;i+=8){
    int ss[8];
    #pragma unroll
    for (int u=0;u<8;u++) ss[u] = lanebci(sL, i+u);
    float vv[8];
    #pragma unroll
    for (int u=0;u<8;u++) vv[u] = bf2f(h0b[(size_t)ss[u]*64 + c]);
    #pragma unroll
    for (int hd=0;hd<4;hd++){
      #pragma unroll
      for (int u=0;u<8;u++) z[hd] += lanebc(preg[hd], i+u)*vv[u];
    }
  }
  for (int i=64;i<dg;i++){
    const float hv = bf2f(h0b[(size_t)srcp[st+i]*64+c]);
    #pragma unroll
    for (int hd=0;hd<4;hd++){
      const float pp = pexp(esc[(size_t)hd*EE + st + i]);
      den[hd] += pp;
      z[hd] += pp*hv;
    }
  }
  #pragma unroll
  for (int hd=0;hd<4;hd++) zb[(size_t)t*256 + hd*64 + c] = f2bf(z[hd]/(den[hd]+1e-16f));
}

// ---------------- fused register-blocked: h1 in LDS; xl2/xr2 = h1@{Wl2,Wr2} ----------------
__global__ __launch_bounds__(256) void k_h1xlxr2(
    const ushort* __restrict__ zb, const float4* __restrict__ Wl1p4,
    const float* __restrict__ bl1, const float* __restrict__ bias1,
    const float4* __restrict__ Wl2p4, const float* __restrict__ bl2,
    const float4* __restrict__ Wr2p4, const float* __restrict__ br2,
    ushort* __restrict__ xl2, ushort* __restrict__ xr2)
{
  const int n0 = blockIdx.x*16;
  const int tid = threadIdx.x;
  __shared__ float zT[256*20];
  __shared__ __align__(16) float4 hs[64][17];
  #pragma unroll
  for (int j=0;j<16;j++) zT[tid*20 + j] = bf2f(zb[(size_t)(n0+j)*256 + tid]);
  __syncthreads();
  {
    const int c = tid, hd = c>>6;
    float acc[16];
    const float b = bl1[c] + bias1[c];
    #pragma unroll
    for (int n=0;n<16;n++) acc[n]=b;
    #pragma unroll 4
    for (int k4=0;k4<16;k4++){
      const float4 w4 = Wl1p4[k4*256 + c];
      #pragma unroll
      for (int kk=0;kk<4;kk++){
        const float wk = (kk==0)?w4.x:(kk==1)?w4.y:(kk==2)?w4.z:w4.w;
        const float* zr = &zT[(hd*64 + k4*4 + kk)*20];
        const float4 z0 = *(const float4*)&zr[0];
        const float4 z1 = *(const float4*)&zr[4];
        const float4 z2 = *(const float4*)&zr[8];
        const float4 z3 = *(const float4*)&zr[12];
        acc[0]+=z0.x*wk; acc[1]+=z0.y*wk; acc[2]+=z0.z*wk; acc[3]+=z0.w*wk;
        acc[4]+=z1.x*wk; acc[5]+=z1.y*wk; acc[6]+=z1.z*wk; acc[7]+=z1.w*wk;
        acc[8]+=z2.x*wk; acc[9]+=z2.y*wk; acc[10]+=z2.z*wk; acc[11]+=z2.w*wk;
        acc[12]+=z3.x*wk; acc[13]+=z3.y*wk; acc[14]+=z3.z*wk; acc[15]+=z3.w*wk;
      }
    }
    float* hsf = (float*)hs;
    const int base = (c>>2)*17*4 + (c&3);
    #pragma unroll
    for (int n=0;n<16;n++) hsf[base + n*4] = elu(acc[n]);
  }
  __syncthreads();
  {
    const int cc = tid & 63, ng = tid >> 6;
    float al[4], ar[4];
    const float bl = bl2[cc], br = br2[cc];
    #pragma unroll
    for (int j=0;j<4;j++){ al[j]=bl; ar[j]=br; }
    #pragma unroll 4
    for (int k4=0;k4<64;k4++){
      const float4 wl = Wl2p4[k4*64 + cc];
      const float4 wr = Wr2p4[k4*64 + cc];
      #pragma unroll
      for (int j=0;j<4;j++){
        const float4 hv = hs[k4][ng*4 + j];
        al[j] += hv.x*wl.x + hv.y*wl.y + hv.z*wl.z + hv.w*wl.w;
        ar[j] += hv.x*wr.x + hv.y*wr.y + hv.z*wr.z + hv.w*wr.w;
      }
    }
    #pragma unroll
    for (int j=0;j<4;j++){
      xl2[(size_t)(n0+ng*4+j)*64 + cc] = f2bf(al[j]);
      xr2[(size_t)(n0+ng*4+j)*64 + cc] = f2bf(ar[j]);
    }
  }
}

// ---------------- layer-2 softmax + aggregate + fused graph-pool ----------------
__global__ __launch_bounds__(256) void k_agg2(
    const float* __restrict__ loopA, const int* __restrict__ cnt,
    const int* __restrict__ start, const int* __restrict__ srcp,
    const ushort* __restrict__ xl, const ushort* __restrict__ xr,
    const float* __restrict__ Wf, const float* __restrict__ bf,
    const float* __restrict__ att, const float* __restrict__ bias,
    const float* __restrict__ esc, const int* __restrict__ batch,
    float* __restrict__ pooled, int* __restrict__ gcnt)
{
  const int t = blockIdx.x*4 + (threadIdx.x>>6);
  const int c = threadIdx.x & 63;
  const int st = start[t], dg = cnt[t];

  float ep = 0.f;
  if (dg>0){
    const float invc = 1.f/(float)dg;
    ep = bf[c];
    #pragma unroll
    for (int j=0;j<9;j++) ep += (loopA[t*12+j]*invc)*Wf[j*64+c];
  }
  const float xlt = bf2f(xl[(size_t)t*64+c]);
  float m = xlt + bf2f(xr[(size_t)t*64+c]) + ep;
  m = (m>=0.f)? m : 0.2f*m;
  const float pS = pexp(wave_sum(att[c]*m));

  int sL=0; float preg=0.f;
  if (c<dg){ sL=srcp[st+c]; preg=pexp(esc[st+c]); }
  float den = wave_sum(preg)+pS;
  float z = pS*xlt;
  const int d1=min(dg,64);
  for (int i=0;i<d1;i+=8){
    int ss[8];
    #pragma unroll
    for (int u=0;u<8;u++) ss[u] = lanebci(sL, i+u);
    float vv[8];
    #pragma unroll
    for (int u=0;u<8;u++) vv[u] = bf2f(xl[(size_t)ss[u]*64 + c]);
    #pragma unroll
    for (int u=0;u<8;u++) z += lanebc(preg, i+u)*vv[u];
  }
  for (int i=64;i<dg;i++){
    const float pp=pexp(esc[st+i]); den+=pp;
    z += pp*bf2f(xl[(size_t)srcp[st+i]*64+c]);
  }
  const float o = z/(den+1e-16f)+bias[c];
  const float r = elu(o);
  const int g = batch[t];
  atomicAdd(&pooled[g*64 + c], r);
  if (c == 0) atomicAdd(&gcnt[g], 1);
}

__global__ void k_out(const float* __restrict__ pooled, const int* __restrict__ gcnt,
                      const float* __restrict__ Wout, const float* __restrict__ bout,
                      float* __restrict__ out){
  int g = blockIdx.x, o = threadIdx.x;   // 128
  float a = 0.f;
  for(int k=0;k<64;k++) a += pooled[g*64 + k] * Wout[k*128 + o];
  float inv = 1.f / fmaxf((float)gcnt[g], 1.f);
  out[g*128 + o] = a*inv + bout[o];
}

extern "C" void kernel_launch(void* const* d_in, const int* in_sizes, int n_in,
                              void* d_out, int out_size, void* d_ws, size_t ws_size,
                              hipStream_t stream) {
  const float* x    = (const float*)d_in[0];
  const int*   ei   = (const int*)  d_in[1];
  const float* ea   = (const float*)d_in[2];
  const int*   batch= (const int*)  d_in[3];
  const float* Wcat = (const float*)d_in[4];
  const float* bcat = (const float*)d_in[5];
  const float* We   = (const float*)d_in[6];
  const float* be   = (const float*)d_in[7];
  const float* Wini = (const float*)d_in[8];
  const float* bini = (const float*)d_in[9];
  const float* Wl1  = (const float*)d_in[10];
  const float* bl1  = (const float*)d_in[11];
  const float* Wr1  = (const float*)d_in[12];
  const float* br1  = (const float*)d_in[13];
  const float* We1  = (const float*)d_in[14];
  const float* att1 = (const float*)d_in[15];
  const float* bias1= (const float*)d_in[16];
  const float* Wl2  = (const float*)d_in[17];
  const float* bl2  = (const float*)d_in[18];
  const float* Wr2  = (const float*)d_in[19];
  const float* br2  = (const float*)d_in[20];
  const float* We2  = (const float*)d_in[21];
  const float* att2 = (const float*)d_in[22];
  const float* bias2= (const float*)d_in[23];
  const float* Wout = (const float*)d_in[24];
  const float* bout = (const float*)d_in[25];
  float* out = (float*)d_out;
  char* ws = (char*)d_ws;

  size_t off = 0;
  auto alloc = [&](size_t bytes)->char*{ char* p = ws + off; off += (bytes + 255) & ~(size_t)255; return p; };
  ushort* h0b   = (ushort*)alloc((size_t)NN*64*2);
  ushort* xl1   = (ushort*)alloc((size_t)NN*256*2);
  ushort* xr1   = (ushort*)alloc((size_t)NN*256*2);
  ushort* zb    = (ushort*)alloc((size_t)NN*256*2);
  ushort* xl2   = (ushort*)alloc((size_t)NN*64*2);
  ushort* xr2   = (ushort*)alloc((size_t)NN*64*2);
  float*  esc   = (float*) alloc((size_t)EE*4*4);   // layer1: [head][EE], raw scores
  float*  esc2  = (float*) alloc((size_t)EE*4);     // layer2: [pos], raw scores
  float*  Wf1   = (float*) alloc((size_t)9*256*4);
  float*  bf1   = (float*) alloc((size_t)256*4);
  float*  Wf2   = (float*) alloc((size_t)9*64*4);
  float*  bf2   = (float*) alloc((size_t)64*4);
  float4* Wl1p4 = (float4*)alloc((size_t)4096*16);
  float4* Wl2p4 = (float4*)alloc((size_t)4096*16);
  float4* Wr2p4 = (float4*)alloc((size_t)4096*16);
  int*    start = (int*)   alloc((size_t)NN*4);
  int*    csr   = (int*)   alloc((size_t)EE*4);
  int*    srcp  = (int*)   alloc((size_t)EE*4);
  int*    tgtp  = (int*)   alloc((size_t)EE*4);
  // ---- contiguous zero region ----
  const size_t zoff = off;
  float*  loopA = (float*) alloc((size_t)NN*12*4);
  int*    cnt   = (int*)   alloc((size_t)NN*4);
  int*    fill  = (int*)   alloc((size_t)NN*4);
  int*    counter = (int*) alloc(256);
  float*  pooled  = (float*)alloc((size_t)GG*64*4);
  int*    gcnt    = (int*)  alloc((size_t)GG*4);
  const size_t zlen = off - zoff;

  hipMemsetAsync(ws + zoff, 0, zlen, stream);

  k_front    <<<22550, 256, 0, stream>>>(x, Wcat, bcat, Wini, bini,
                                         Wl1, bl1, Wr1, br1, h0b, xl1, xr1,
                                         ei, ea, loopA, cnt,
                                         We, be, We1, We2, Wl2, Wr2,
                                         Wf1, bf1, Wf2, bf2, Wl1p4, Wl2p4, Wr2p4);
  k_alloc    <<<(NN+255)/256, 256, 0, stream>>>(cnt, start, counter);
  k_scatter  <<<(EE+255)/256, 256, 0, stream>>>(ei, start, fill, csr, srcp, tgtp);
  k_score<256><<<EE/64, 256, 0, stream>>>(ea, csr, srcp, tgtp, xl1, xr1, Wf1, bf1, att1, esc);
  k_agg1     <<<NN/4, 256, 0, stream>>>(loopA, cnt, start, srcp, h0b, xl1, xr1, Wf1, bf1, att1, esc, zb);
  k_h1xlxr2  <<<NN/16, 256, 0, stream>>>(zb, Wl1p4, bl1, bias1, Wl2p4, bl2, Wr2p4, br2, xl2, xr2);
  k_score<64><<<EE/64, 256, 0, stream>>>(ea, csr, srcp, tgtp, xl2, xr2, Wf2, bf2, att2, esc2);
  k_agg2     <<<NN/4, 256, 0, stream>>>(loopA, cnt, start, srcp, xl2, xr2, Wf2, bf2, att2, bias2,
                                        esc2, batch, pooled, gcnt);
  k_out      <<<GG, 128, 0, stream>>>(pooled, gcnt, Wout, bout, out);
}

// Round 15
// 299.129 us; speedup vs baseline: 1.0713x; 1.0713x over previous
//
#include <hip/hip_runtime.h>
#include <hip/hip_bf16.h>

#define NN 20000
#define EE 320000
#define GG 256

__device__ __forceinline__ float lanebc(float v, int l){
  return __uint_as_float(__builtin_amdgcn_readlane(__float_as_uint(v), (unsigned)l));
}
__device__ __forceinline__ int lanebci(int v, int l){
  return __builtin_amdgcn_readlane(v, (unsigned)l);
}
__device__ __forceinline__ float wave_sum(float v){
  #pragma unroll
  for(int m=32;m>0;m>>=1) v += __shfl_xor(v, m, 64);
  return v;
}
__device__ __forceinline__ float elu(float o){
  return (o > 0.f) ? o : (__expf(o) - 1.f);
}
// softmax exp without max-pass: shift-invariant, clamp prevents overflow (scores are O(5))
__device__ __forceinline__ float pexp(float e){ return __expf(fminf(e, 60.f)); }
// bf16 pack/unpack
__device__ __forceinline__ float bf2f(ushort u){ return __uint_as_float((unsigned)u << 16); }
__device__ __forceinline__ ushort f2bf(float f){
  unsigned x = __float_as_uint(f);
  return (ushort)((x + 0x7FFFu + ((x >> 16) & 1u)) >> 16);
}
__device__ __forceinline__ float2 up2(unsigned w){
  return make_float2(__uint_as_float(w << 16), __uint_as_float(w & 0xFFFF0000u));
}

// ---------------- weights prep: fold edge weights + float4-by-4k packs (one launch) ----------------
__global__ void k_weights(const float* __restrict__ We9, const float* __restrict__ be,
                          const float* __restrict__ We1, const float* __restrict__ We2,
                          const float* __restrict__ Wl1, const float* __restrict__ Wl2,
                          const float* __restrict__ Wr2,
                          float* __restrict__ Wf1, float* __restrict__ bf1,
                          float* __restrict__ Wf2, float* __restrict__ bf2,
                          float4* __restrict__ Wl1p4, float4* __restrict__ Wl2p4,
                          float4* __restrict__ Wr2p4){
  const int b = blockIdx.x;
  const int tid = threadIdx.x;
  if (b < 48){
    const int idx = (b%16)*256 + tid;
    const int seg = b/16;
    if (seg == 0){
      const int k4 = idx>>8, c = idx&255;
      Wl1p4[idx] = make_float4(Wl1[(4*k4+0)*256+c], Wl1[(4*k4+1)*256+c],
                               Wl1[(4*k4+2)*256+c], Wl1[(4*k4+3)*256+c]);
    } else if (seg == 1){
      const int k4 = idx>>6, cc = idx&63;
      Wl2p4[idx] = make_float4(Wl2[(4*k4+0)*64+cc], Wl2[(4*k4+1)*64+cc],
                               Wl2[(4*k4+2)*64+cc], Wl2[(4*k4+3)*64+cc]);
    } else {
      const int k4 = idx>>6, cc = idx&63;
      Wr2p4[idx] = make_float4(Wr2[(4*k4+0)*64+cc], Wr2[(4*k4+1)*64+cc],
                               Wr2[(4*k4+2)*64+cc], Wr2[(4*k4+3)*64+cc]);
    }
  } else if (b == 48){
    const int c = tid; // 256
    #pragma unroll
    for (int j=0;j<9;j++){
      float a = 0.f;
      #pragma unroll
      for (int k=0;k<32;k++) a += We9[j*32+k]*We1[k*256+c];
      Wf1[j*256+c] = a;
    }
    float bb = 0.f;
    #pragma unroll
    for (int k=0;k<32;k++) bb += be[k]*We1[k*256+c];
    bf1[c] = bb;
  } else {
    if (tid < 64){
      const int c = tid;
      #pragma unroll
      for (int j=0;j<9;j++){
        float a = 0.f;
        #pragma unroll
        for (int k=0;k<32;k++) a += We9[j*32+k]*We2[k*64+c];
        Wf2[j*64+c] = a;
      }
      float bb = 0.f;
      #pragma unroll
      for (int k=0;k<32;k++) bb += be[k]*We2[k*64+c];
      bf2[c] = bb;
    }
  }
}

// ---------------- in-degree count (1 atomic/edge) ----------------
__global__ void k_cnt(const int* __restrict__ ei, int* __restrict__ cnt){
  int e = blockIdx.x*256 + threadIdx.x;
  if (e < EE) atomicAdd(&cnt[ei[EE+e]], 1);
}

__global__ void k_alloc(const int* __restrict__ cnt, int* __restrict__ start, int* __restrict__ counter){
  int i = blockIdx.x*blockDim.x + threadIdx.x;
  if (i < NN) start[i] = atomicAdd(counter, cnt[i]);
}

__global__ void k_scatter(const int* __restrict__ ei, const int* __restrict__ start,
                          int* __restrict__ fill, int* __restrict__ csr,
                          int* __restrict__ srcp, int* __restrict__ tgtp){
  int e = blockIdx.x*blockDim.x + threadIdx.x;
  if (e >= EE) return;
  int t = ei[EE + e];
  int p = start[t] + atomicAdd(&fill[t], 1);
  csr[p] = e;
  srcp[p] = ei[e];
  tgtp[p] = t;
}

// ---------------- loopA (per-node ea sums) from CSR, no atomics ----------------
// one wave per node; lanes form a 7-edge x 9-feature tile: i0=lane/9, j=lane%9
__global__ __launch_bounds__(256) void k_loopA(
    const int* __restrict__ csr, const int* __restrict__ start,
    const int* __restrict__ cnt, const float* __restrict__ ea,
    float* __restrict__ loopA)
{
  const int t = blockIdx.x*4 + (threadIdx.x>>6);
  const int lane = threadIdx.x & 63;
  const int st = start[t], dg = cnt[t];
  const int i0 = lane/9, j = lane - 9*i0;   // lane 63 -> i0=7 (idle)
  float s = 0.f;
  if (i0 < 7){
    for (int i=i0; i<dg; i+=7)
      s += ea[(size_t)csr[st+i]*9 + j];
  }
  float tot = s;
  #pragma unroll
  for (int k=1;k<7;k++) tot += __shfl(s, lane + 9*k, 64);
  if (lane < 9) loopA[t*12 + lane] = tot;
}

// ---------------- fused node-MLP + layer-1 transform: h0 in LDS, emits h0b(bf16), xl1/xr1(bf16) ----------------
__global__ __launch_bounds__(256) void k_xlxr1f(
    const float* __restrict__ x, const float* __restrict__ Wcat,
    const float* __restrict__ bcat, const float* __restrict__ Wini,
    const float* __restrict__ bini, const float* __restrict__ Wl,
    const float* __restrict__ bl, const float* __restrict__ Wr,
    const float* __restrict__ br, ushort* __restrict__ h0b,
    ushort* __restrict__ xl, ushort* __restrict__ xr)
{
  const int n0 = blockIdx.x*8;
  const int tid = threadIdx.x;
  __shared__ float xs[8][25];
  __shared__ float sv[8][33];
  __shared__ __align__(16) float hsT[64][8];
  if (tid < 192){ int n=tid/24, j=tid%24; xs[n][j] = x[(size_t)(n0+n)*24 + j]; }
  __syncthreads();
  { // categorical hidden: 8 nodes x 32 ch
    const int n = tid>>5, cc = tid&31;
    float a = bcat[cc];
    #pragma unroll
    for (int k=0;k<16;k++) a += xs[n][k]*Wcat[k*32+cc];
    sv[n][cc] = fmaxf(a, 0.f);
  }
  __syncthreads();
  #pragma unroll
  for (int i=tid;i<512;i+=256){ // h0: 8 nodes x 64 ch
    const int n = i>>6, c = i&63;
    float a = bini[c];
    #pragma unroll
    for (int k=0;k<8;k++)  a += xs[n][16+k]*Wini[k*64+c];
    #pragma unroll
    for (int k=0;k<32;k++) a += sv[n][k]*Wini[(8+k)*64+c];
    const float r = fmaxf(a, 0.f);
    hsT[c][n] = r;
    h0b[(size_t)(n0+n)*64 + c] = f2bf(r);
  }
  __syncthreads();
  const int c = tid;   // 256
  float accl[8], accr[8];
  const float blv = bl[c], brv = br[c];
  #pragma unroll
  for(int n=0;n<8;n++){ accl[n]=blv; accr[n]=brv; }
  for(int k=0;k<64;k++){
    const float wl = Wl[k*256 + c];
    const float wr = Wr[k*256 + c];
    const float4 ha = *(const float4*)&hsT[k][0];
    const float4 hb = *(const float4*)&hsT[k][4];
    accl[0]+=ha.x*wl; accr[0]+=ha.x*wr; accl[1]+=ha.y*wl; accr[1]+=ha.y*wr;
    accl[2]+=ha.z*wl; accr[2]+=ha.z*wr; accl[3]+=ha.w*wl; accr[3]+=ha.w*wr;
    accl[4]+=hb.x*wl; accr[4]+=hb.x*wr; accl[5]+=hb.y*wl; accr[5]+=hb.y*wr;
    accl[6]+=hb.z*wl; accr[6]+=hb.z*wr; accl[7]+=hb.w*wl; accr[7]+=hb.w*wr;
  }
  #pragma unroll
  for(int n=0;n<8;n++){
    xl[(size_t)(n0+n)*256 + c] = f2bf(accl[n]);
    xr[(size_t)(n0+n)*256 + c] = f2bf(accr[n]);
  }
}

// ---------------- edge-parallel GATv2 scores (K=9 folded, bf16 gathers) ----------------
// esc layout: [head][EE], stores RAW scores. EXACT round-10 codegen — epilogue is
// codegen-fragile: any change (store layout, transcendental in store path) triples VGPR.
template<int F>
__global__ __launch_bounds__(256) void k_score(const float* __restrict__ ea, const int* __restrict__ csr,
                        const int* __restrict__ srcp, const int* __restrict__ tgtp,
                        const ushort* __restrict__ xl, const ushort* __restrict__ xr,
                        const float* __restrict__ Wf, const float* __restrict__ bf,
                        const float* __restrict__ att, float* __restrict__ esc)
{
  constexpr int HP  = (F == 256) ? 2 : 1;
  constexpr int CPL = (F == 256) ? 8 : 4;
  const int tid  = threadIdx.x;
  const int lane = tid & 63;
  const int w    = tid >> 6;
  const int p0   = blockIdx.x * 64;

  __shared__ float ea_sT[9][64];
  __shared__ float Wf_s[9*F];
  __shared__ float bf_s[F];
  __shared__ int csr_s[64], src_s[64], tgt_s[64];

  if (tid < 64) { csr_s[tid] = csr[p0+tid]; src_s[tid] = srcp[p0+tid]; tgt_s[tid] = tgtp[p0+tid]; }
  __syncthreads();
  for (int i = tid; i < 576; i += 256){ int j = i>>6, ed = i&63; ea_sT[j][ed] = ea[(size_t)csr_s[ed]*9 + j]; }
  for (int i = tid; i < (9*F)/4; i += 256) ((float4*)Wf_s)[i] = ((const float4*)Wf)[i];
  if (tid < F) bf_s[tid] = bf[tid];
  __syncthreads();

  const int g = lane >> 4, t = lane & 15;
  const int eb = w*16 + g*4;

  #pragma unroll
  for (int hp = 0; hp < HP; ++hp) {
    const int c = hp*(F/HP) + t*CPL;
    float bfv[CPL];
    *(float4*)&bfv[0] = *(const float4*)&bf_s[c];
    if (CPL==8) *(float4*)&bfv[4] = *(const float4*)&bf_s[c+4];
    float acc[4][CPL];
    #pragma unroll
    for (int j=0;j<4;j++)
      #pragma unroll
      for(int q=0;q<CPL;q++) acc[j][q]=bfv[q];
    #pragma unroll
    for (int k=0;k<9;k++){
      const float4 ev = *(const float4*)&ea_sT[k][eb];
      float wv[CPL];
      *(float4*)&wv[0] = *(const float4*)&Wf_s[k*F + c];
      if (CPL==8) *(float4*)&wv[4] = *(const float4*)&Wf_s[k*F + c + 4];
      #pragma unroll
      for (int q=0;q<CPL;q++){
        acc[0][q] += ev.x*wv[q]; acc[1][q] += ev.y*wv[q];
        acc[2][q] += ev.z*wv[q]; acc[3][q] += ev.w*wv[q];
      }
    }
    float attv[CPL];
    *(float4*)&attv[0] = *(const float4*)&att[c];
    if (CPL==8) *(float4*)&attv[4] = *(const float4*)&att[c+4];
    float partial[4];
    #pragma unroll
    for (int j=0;j<4;j++){
      const int s  = src_s[eb+j];
      const int tg = tgt_s[eb+j];
      float xlv[CPL], xrv[CPL];
      if (CPL==8){
        const uint4 a = *(const uint4*)&xl[(size_t)s*F + c];
        const uint4 b = *(const uint4*)&xr[(size_t)tg*F + c];
        float2 p;
        p=up2(a.x); xlv[0]=p.x; xlv[1]=p.y;  p=up2(a.y); xlv[2]=p.x; xlv[3]=p.y;
        p=up2(a.z); xlv[4]=p.x; xlv[5]=p.y;  p=up2(a.w); xlv[6]=p.x; xlv[7]=p.y;
        p=up2(b.x); xrv[0]=p.x; xrv[1]=p.y;  p=up2(b.y); xrv[2]=p.x; xrv[3]=p.y;
        p=up2(b.z); xrv[4]=p.x; xrv[5]=p.y;  p=up2(b.w); xrv[6]=p.x; xrv[7]=p.y;
      } else {
        const uint2 a = *(const uint2*)&xl[(size_t)s*F + c];
        const uint2 b = *(const uint2*)&xr[(size_t)tg*F + c];
        float2 p;
        p=up2(a.x); xlv[0]=p.x; xlv[1]=p.y;  p=up2(a.y); xlv[2]=p.x; xlv[3]=p.y;
        p=up2(b.x); xrv[0]=p.x; xrv[1]=p.y;  p=up2(b.y); xrv[2]=p.x; xrv[3]=p.y;
      }
      float sum = 0.f;
      #pragma unroll
      for (int q=0;q<CPL;q++){
        float m = acc[j][q] + xlv[q] + xrv[q];
        m = (m >= 0.f) ? m : 0.2f*m;
        sum += attv[q]*m;
      }
      partial[j] = sum;
    }
    #pragma unroll
    for (int j=0;j<4;j++){
      partial[j] += __shfl_xor(partial[j], 1, 64);
      partial[j] += __shfl_xor(partial[j], 2, 64);
      partial[j] += __shfl_xor(partial[j], 4, 64);
      if (F==64) partial[j] += __shfl_xor(partial[j], 8, 64);
    }
    if (F==256){
      if ((t & 7) == 0){
        const int h = hp*2 + (t>>3);
        #pragma unroll
        for (int j=0;j<4;j++) esc[(size_t)h*EE + p0 + eb + j] = partial[j];
      }
    } else {
      if (t == 0){
        #pragma unroll
        for (int j=0;j<4;j++) esc[p0 + eb + j] = partial[j];
      }
    }
  }
}

// ---------------- layer-1 softmax + h-space aggregate (no max pass): zb[N,4,64] bf16 ----------------
__global__ __launch_bounds__(256) void k_agg1(
    const float* __restrict__ loopA, const int* __restrict__ cnt,
    const int* __restrict__ start, const int* __restrict__ srcp,
    const ushort* __restrict__ h0b, const ushort* __restrict__ xl, const ushort* __restrict__ xr,
    const float* __restrict__ Wf, const float* __restrict__ bf,
    const float* __restrict__ att, const float* __restrict__ esc,
    ushort* __restrict__ zb)
{
  const int t = blockIdx.x*4 + (threadIdx.x>>6);
  const int c = threadIdx.x & 63;
  const int st = start[t], dg = cnt[t];

  float epb[4];
  if (dg > 0){
    const float invc = 1.f/(float)dg;
    float la[9];
    #pragma unroll
    for (int j=0;j<9;j++) la[j] = loopA[t*12+j]*invc;
    #pragma unroll
    for (int hd=0;hd<4;hd++){
      float ep = bf[hd*64+c];
      #pragma unroll
      for (int j=0;j<9;j++) ep += la[j]*Wf[j*256 + hd*64 + c];
      epb[hd] = ep;
    }
  } else {
    #pragma unroll
    for (int hd=0;hd<4;hd++) epb[hd]=0.f;
  }
  const float h0t = bf2f(h0b[(size_t)t*64 + c]);
  float preg[4], den[4], z[4];
  #pragma unroll
  for (int hd=0;hd<4;hd++){
    float m = bf2f(xl[(size_t)t*256 + hd*64 + c]) + bf2f(xr[(size_t)t*256 + hd*64 + c]) + epb[hd];
    m = (m>=0.f)? m : 0.2f*m;
    const float pS = pexp(wave_sum(att[hd*64+c]*m));
    den[hd] = pS;
    z[hd] = pS*h0t;
  }

  int sL = 0;
  #pragma unroll
  for (int hd=0;hd<4;hd++) preg[hd] = 0.f;
  if (c < dg){
    sL = srcp[st+c];
    #pragma unroll
    for (int hd=0;hd<4;hd++) preg[hd] = pexp(esc[(size_t)hd*EE + st + c]);
  }
  #pragma unroll
  for (int hd=0;hd<4;hd++) den[hd] += wave_sum(preg[hd]);

  const int d1 = min(dg,64);
  for (int i=0;i<d1;i+=8){
    int ss[8];
    #pragma unroll
    for (int u=0;u<8;u++) ss[u] = lanebci(sL, i+u);
    float vv[8];
    #pragma unroll
    for (int u=0;u<8;u++) vv[u] = bf2f(h0b[(size_t)ss[u]*64 + c]);
    #pragma unroll
    for (int hd=0;hd<4;hd++){
      #pragma unroll
      for (int u=0;u<8;u++) z[hd] += lanebc(preg[hd], i+u)*vv[u];
    }
  }
  for (int i=64;i<dg;i++){
    const float hv = bf2f(h0b[(size_t)srcp[st+i]*64+c]);
    #pragma unroll
    for (int hd=0;hd<4;hd++){
      const float pp = pexp(esc[(size_t)hd*EE + st + i]);
      den[hd] += pp;
      z[hd] += pp*hv;
    }
  }
  #pragma unroll
  for (int hd=0;hd<4;hd++) zb[(size_t)t*256 + hd*64 + c] = f2bf(z[hd]/(den[hd]+1e-16f));
}

// ---------------- fused register-blocked: h1 in LDS; xl2/xr2 = h1@{Wl2,Wr2} ----------------
__global__ __launch_bounds__(256) void k_h1xlxr2(
    const ushort* __restrict__ zb, const float4* __restrict__ Wl1p4,
    const float* __restrict__ bl1, const float* __restrict__ bias1,
    const float4* __restrict__ Wl2p4, const float* __restrict__ bl2,
    const float4* __restrict__ Wr2p4, const float* __restrict__ br2,
    ushort* __restrict__ xl2, ushort* __restrict__ xr2)
{
  const int n0 = blockIdx.x*16;
  const int tid = threadIdx.x;
  __shared__ float zT[256*20];
  __shared__ __align__(16) float4 hs[64][17];
  #pragma unroll
  for (int j=0;j<16;j++) zT[tid*20 + j] = bf2f(zb[(size_t)(n0+j)*256 + tid]);
  __syncthreads();
  {
    const int c = tid, hd = c>>6;
    float acc[16];
    const float b = bl1[c] + bias1[c];
    #pragma unroll
    for (int n=0;n<16;n++) acc[n]=b;
    #pragma unroll 4
    for (int k4=0;k4<16;k4++){
      const float4 w4 = Wl1p4[k4*256 + c];
      #pragma unroll
      for (int kk=0;kk<4;kk++){
        const float wk = (kk==0)?w4.x:(kk==1)?w4.y:(kk==2)?w4.z:w4.w;
        const float* zr = &zT[(hd*64 + k4*4 + kk)*20];
        const float4 z0 = *(const float4*)&zr[0];
        const float4 z1 = *(const float4*)&zr[4];
        const float4 z2 = *(const float4*)&zr[8];
        const float4 z3 = *(const float4*)&zr[12];
        acc[0]+=z0.x*wk; acc[1]+=z0.y*wk; acc[2]+=z0.z*wk; acc[3]+=z0.w*wk;
        acc[4]+=z1.x*wk; acc[5]+=z1.y*wk; acc[6]+=z1.z*wk; acc[7]+=z1.w*wk;
        acc[8]+=z2.x*wk; acc[9]+=z2.y*wk; acc[10]+=z2.z*wk; acc[11]+=z2.w*wk;
        acc[12]+=z3.x*wk; acc[13]+=z3.y*wk; acc[14]+=z3.z*wk; acc[15]+=z3.w*wk;
      }
    }
    float* hsf = (float*)hs;
    const int base = (c>>2)*17*4 + (c&3);
    #pragma unroll
    for (int n=0;n<16;n++) hsf[base + n*4] = elu(acc[n]);
  }
  __syncthreads();
  {
    const int cc = tid & 63, ng = tid >> 6;
    float al[4], ar[4];
    const float bl = bl2[cc], br = br2[cc];
    #pragma unroll
    for (int j=0;j<4;j++){ al[j]=bl; ar[j]=br; }
    #pragma unroll 4
    for (int k4=0;k4<64;k4++){
      const float4 wl = Wl2p4[k4*64 + cc];
      const float4 wr = Wr2p4[k4*64 + cc];
      #pragma unroll
      for (int j=0;j<4;j++){
        const float4 hv = hs[k4][ng*4 + j];
        al[j] += hv.x*wl.x + hv.y*wl.y + hv.z*wl.z + hv.w*wl.w;
        ar[j] += hv.x*wr.x + hv.y*wr.y + hv.z*wr.z + hv.w*wr.w;
      }
    }
    #pragma unroll
    for (int j=0;j<4;j++){
      xl2[(size_t)(n0+ng*4+j)*64 + cc] = f2bf(al[j]);
      xr2[(size_t)(n0+ng*4+j)*64 + cc] = f2bf(ar[j]);
    }
  }
}

// ---------------- layer-2 softmax + aggregate + fused graph-pool ----------------
__global__ __launch_bounds__(256) void k_agg2(
    const float* __restrict__ loopA, const int* __restrict__ cnt,
    const int* __restrict__ start, const int* __restrict__ srcp,
    const ushort* __restrict__ xl, const ushort* __restrict__ xr,
    const float* __restrict__ Wf, const float* __restrict__ bf,
    const float* __restrict__ att, const float* __restrict__ bias,
    const float* __restrict__ esc, const int* __restrict__ batch,
    float* __restrict__ pooled, int* __restrict__ gcnt)
{
  const int t = blockIdx.x*4 + (threadIdx.x>>6);
  const int c = threadIdx.x & 63;
  const int st = start[t], dg = cnt[t];

  float ep = 0.f;
  if (dg>0){
    const float invc = 1.f/(float)dg;
    ep = bf[c];
    #pragma unroll
    for (int j=0;j<9;j++) ep += (loopA[t*12+j]*invc)*Wf[j*64+c];
  }
  const float xlt = bf2f(xl[(size_t)t*64+c]);
  float m = xlt + bf2f(xr[(size_t)t*64+c]) + ep;
  m = (m>=0.f)? m : 0.2f*m;
  const float pS = pexp(wave_sum(att[c]*m));

  int sL=0; float preg=0.f;
  if (c<dg){ sL=srcp[st+c]; preg=pexp(esc[st+c]); }
  float den = wave_sum(preg)+pS;
  float z = pS*xlt;
  const int d1=min(dg,64);
  for (int i=0;i<d1;i+=8){
    int ss[8];
    #pragma unroll
    for (int u=0;u<8;u++) ss[u] = lanebci(sL, i+u);
    float vv[8];
    #pragma unroll
    for (int u=0;u<8;u++) vv[u] = bf2f(xl[(size_t)ss[u]*64 + c]);
    #pragma unroll
    for (int u=0;u<8;u++) z += lanebc(preg, i+u)*vv[u];
  }
  for (int i=64;i<dg;i++){
    const float pp=pexp(esc[st+i]); den+=pp;
    z += pp*bf2f(xl[(size_t)srcp[st+i]*64+c]);
  }
  const float o = z/(den+1e-16f)+bias[c];
  const float r = elu(o);
  const int g = batch[t];
  atomicAdd(&pooled[g*64 + c], r);
  if (c == 0) atomicAdd(&gcnt[g], 1);
}

__global__ void k_out(const float* __restrict__ pooled, const int* __restrict__ gcnt,
                      const float* __restrict__ Wout, const float* __restrict__ bout,
                      float* __restrict__ out){
  int g = blockIdx.x, o = threadIdx.x;   // 128
  float a = 0.f;
  for(int k=0;k<64;k++) a += pooled[g*64 + k] * Wout[k*128 + o];
  float inv = 1.f / fmaxf((float)gcnt[g], 1.f);
  out[g*128 + o] = a*inv + bout[o];
}

extern "C" void kernel_launch(void* const* d_in, const int* in_sizes, int n_in,
                              void* d_out, int out_size, void* d_ws, size_t ws_size,
                              hipStream_t stream) {
  const float* x    = (const float*)d_in[0];
  const int*   ei   = (const int*)  d_in[1];
  const float* ea   = (const float*)d_in[2];
  const int*   batch= (const int*)  d_in[3];
  const float* Wcat = (const float*)d_in[4];
  const float* bcat = (const float*)d_in[5];
  const float* We   = (const float*)d_in[6];
  const float* be   = (const float*)d_in[7];
  const float* Wini = (const float*)d_in[8];
  const float* bini = (const float*)d_in[9];
  const float* Wl1  = (const float*)d_in[10];
  const float* bl1  = (const float*)d_in[11];
  const float* Wr1  = (const float*)d_in[12];
  const float* br1  = (const float*)d_in[13];
  const float* We1  = (const float*)d_in[14];
  const float* att1 = (const float*)d_in[15];
  const float* bias1= (const float*)d_in[16];
  const float* Wl2  = (const float*)d_in[17];
  const float* bl2  = (const float*)d_in[18];
  const float* Wr2  = (const float*)d_in[19];
  const float* br2  = (const float*)d_in[20];
  const float* We2  = (const float*)d_in[21];
  const float* att2 = (const float*)d_in[22];
  const float* bias2= (const float*)d_in[23];
  const float* Wout = (const float*)d_in[24];
  const float* bout = (const float*)d_in[25];
  float* out = (float*)d_out;
  char* ws = (char*)d_ws;

  size_t off = 0;
  auto alloc = [&](size_t bytes)->char*{ char* p = ws + off; off += (bytes + 255) & ~(size_t)255; return p; };
  ushort* h0b   = (ushort*)alloc((size_t)NN*64*2);
  ushort* xl1   = (ushort*)alloc((size_t)NN*256*2);
  ushort* xr1   = (ushort*)alloc((size_t)NN*256*2);
  ushort* zb    = (ushort*)alloc((size_t)NN*256*2);
  ushort* xl2   = (ushort*)alloc((size_t)NN*64*2);
  ushort* xr2   = (ushort*)alloc((size_t)NN*64*2);
  float*  esc   = (float*) alloc((size_t)EE*4*4);   // layer1: [head][EE], raw scores
  float*  esc2  = (float*) alloc((size_t)EE*4);     // layer2: [pos], raw scores
  float*  loopA = (float*) alloc((size_t)NN*12*4);  // written fully by k_loopA
  float*  Wf1   = (float*) alloc((size_t)9*256*4);
  float*  bf1   = (float*) alloc((size_t)256*4);
  float*  Wf2   = (float*) alloc((size_t)9*64*4);
  float*  bf2   = (float*) alloc((size_t)64*4);
  float4* Wl1p4 = (float4*)alloc((size_t)4096*16);
  float4* Wl2p4 = (float4*)alloc((size_t)4096*16);
  float4* Wr2p4 = (float4*)alloc((size_t)4096*16);
  int*    start = (int*)   alloc((size_t)NN*4);
  int*    csr   = (int*)   alloc((size_t)EE*4);
  int*    srcp  = (int*)   alloc((size_t)EE*4);
  int*    tgtp  = (int*)   alloc((size_t)EE*4);
  // ---- contiguous zero region ----
  const size_t zoff = off;
  int*    cnt   = (int*)   alloc((size_t)NN*4);
  int*    fill  = (int*)   alloc((size_t)NN*4);
  int*    counter = (int*) alloc(256);
  float*  pooled  = (float*)alloc((size_t)GG*64*4);
  int*    gcnt    = (int*)  alloc((size_t)GG*4);
  const size_t zlen = off - zoff;

  hipMemsetAsync(ws + zoff, 0, zlen, stream);

  k_weights  <<<50, 256, 0, stream>>>(We, be, We1, We2, Wl1, Wl2, Wr2,
                                      Wf1, bf1, Wf2, bf2, Wl1p4, Wl2p4, Wr2p4);
  k_cnt      <<<(EE+255)/256, 256, 0, stream>>>(ei, cnt);
  k_alloc    <<<(NN+255)/256, 256, 0, stream>>>(cnt, start, counter);
  k_scatter  <<<(EE+255)/256, 256, 0, stream>>>(ei, start, fill, csr, srcp, tgtp);
  k_loopA    <<<NN/4, 256, 0, stream>>>(csr, start, cnt, ea, loopA);
  k_xlxr1f   <<<NN/8, 256, 0, stream>>>(x, Wcat, bcat, Wini, bini,
                                        Wl1, bl1, Wr1, br1, h0b, xl1, xr1);
  k_score<256><<<EE/64, 256, 0, stream>>>(ea, csr, srcp, tgtp, xl1, xr1, Wf1, bf1, att1, esc);
  k_agg1     <<<NN/4, 256, 0, stream>>>(loopA, cnt, start, srcp, h0b, xl1, xr1, Wf1, bf1, att1, esc, zb);
  k_h1xlxr2  <<<NN/16, 256, 0, stream>>>(zb, Wl1p4, bl1, bias1, Wl2p4, bl2, Wr2p4, br2, xl2, xr2);
  k_score<64><<<EE/64, 256, 0, stream>>>(ea, csr, srcp, tgtp, xl2, xr2, Wf2, bf2, att2, esc2);
  k_agg2     <<<NN/4, 256, 0, stream>>>(loopA, cnt, start, srcp, xl2, xr2, Wf2, bf2, att2, bias2,
                                        esc2, batch, pooled, gcnt);
  k_out      <<<GG, 128, 0, stream>>>(pooled, gcnt, Wout, bout, out);
}